// Round 3
// baseline (728.163 us; speedup 1.0000x reference)
//
#include <hip/hip_runtime.h>
#include <math.h>

#define BATCH 8
#define CCH 256
#define HW 40000
#define HW4 (HW / 4)          // 10000 float4 pixel-groups per batch
#define KSEL 8000
#define EPS_LN 1e-6f
#define EPS_COS 1e-8f
#define SLICES 40             // blocks per batch for hist2/sum passes
#define SLICE_LEN (HW / SLICES)
#define CSLICE 4              // channel slices per pixel-group
#define CPS (CCH / CSLICE)    // 64 channels per slice
#define BPB 157               // stats blocks per batch: ceil(10000/64)

// ---- workspace layout (uint/float units) ----
#define OFF_SCORE   0
#define OFF_CONTRIB 320000
#define OFF_HIST1   640000
#define OFF_HIST2   1164288
#define OFF_PREFIX  1688576
#define OFF_REM1    1688584
#define OFF_TKEY    1688592
#define OFF_REM2    1688600
#define OFF_TIE     1688608
#define OFF_BSUMS   1688616
#define OFF_DONE    1688624

__device__ __forceinline__ unsigned int mono_key(float x) {
  unsigned int u = __float_as_uint(x);
  return (u & 0x80000000u) ? ~u : (u | 0x80000000u);
}

// Zero hist1+hist2 (4 MB) + tie/bsums/done scalars.
__global__ __launch_bounds__(256) void zero_kernel(unsigned int* __restrict__ ws) {
  const int n4 = (2 * BATCH * 65536) / 4;
  uint4* p = (uint4*)(ws + OFF_HIST1);
  uint4 z = {0u, 0u, 0u, 0u};
  for (int i = blockIdx.x * blockDim.x + threadIdx.x; i < n4; i += gridDim.x * blockDim.x)
    p[i] = z;
  if (blockIdx.x == 0 && threadIdx.x < 17) ws[OFF_TIE + threadIdx.x] = 0u;
}

// Block = 64 float4-pixel-groups x 4 channel-slices. Each thread streams 64
// channels of both tensors (float4 = 16B/lane loads), LDS-combines the 20
// partial moments, slice-0 threads finish score/contrib and hist1 atomics.
__global__ __launch_bounds__(256) void stats_kernel(
    const float* __restrict__ A, const float* __restrict__ B,
    float* __restrict__ score, float* __restrict__ contrib,
    unsigned int* __restrict__ ws) {
  __shared__ float sm[CSLICE][20][64];  // [slice][moment*4+j][pix] — stride-1 in pix: conflict-free
  int b = blockIdx.x / BPB;
  int blk = blockIdx.x - b * BPB;
  int pix = threadIdx.x & 63;
  int slice = threadIdx.x >> 6;
  int p4 = blk * 64 + pix;
  bool active = p4 < HW4;

  float acc[20];
#pragma unroll
  for (int m = 0; m < 20; ++m) acc[m] = 0.f;

  if (active) {
    const float4* a  = (const float4*)A + ((size_t)b * CCH + slice * CPS) * HW4 + p4;
    const float4* bb = (const float4*)B + ((size_t)b * CCH + slice * CPS) * HW4 + p4;
#pragma unroll 4
    for (int c = 0; c < CPS; ++c) {
      float4 x = a[(size_t)c * HW4];
      float4 y = bb[(size_t)c * HW4];
      float xs[4] = {x.x, x.y, x.z, x.w};
      float ys[4] = {y.x, y.y, y.z, y.w};
#pragma unroll
      for (int j = 0; j < 4; ++j) {
        acc[0 * 4 + j] += xs[j];
        acc[1 * 4 + j] = fmaf(xs[j], xs[j], acc[1 * 4 + j]);
        acc[2 * 4 + j] += ys[j];
        acc[3 * 4 + j] = fmaf(ys[j], ys[j], acc[3 * 4 + j]);
        acc[4 * 4 + j] = fmaf(xs[j], ys[j], acc[4 * 4 + j]);
      }
    }
  }
#pragma unroll
  for (int m = 0; m < 20; ++m) sm[slice][m][pix] = acc[m];
  __syncthreads();

  if (slice == 0 && active) {
    float v[20];
#pragma unroll
    for (int m = 0; m < 20; ++m)
      v[m] = sm[0][m][pix] + sm[1][m][pix] + sm[2][m][pix] + sm[3][m][pix];

    float scv[4], cov[4];
    const float invC = 1.0f / (float)CCH;
#pragma unroll
    for (int j = 0; j < 4; ++j) {
      float sa = v[0 * 4 + j], ssa = v[1 * 4 + j];
      float sb = v[2 * 4 + j], ssb = v[3 * 4 + j], dab = v[4 * 4 + j];
      scv[j] = ssa;
      float mua = sa * invC, mub = sb * invC;
      float cssa = fmaxf(ssa - (float)CCH * mua * mua, 0.f);
      float cssb = fmaxf(ssb - (float)CCH * mub * mub, 0.f);
      float cdot = dab - (float)CCH * mua * mub;
      float siga = sqrtf(cssa / (float)(CCH - 1)) + EPS_LN;
      float sigb = sqrtf(cssb / (float)(CCH - 1)) + EPS_LN;
      float num = cdot / (siga * sigb);
      float na = sqrtf(cssa) / siga;
      float nb = sqrtf(cssb) / sigb;
      cov[j] = 1.0f - num / (fmaxf(na, EPS_COS) * fmaxf(nb, EPS_COS));
    }
    int out = b * HW + p4 * 4;
    *(float4*)(score + out)   = make_float4(scv[0], scv[1], scv[2], scv[3]);
    *(float4*)(contrib + out) = make_float4(cov[0], cov[1], cov[2], cov[3]);
    unsigned int* h = ws + OFF_HIST1 + (b << 16);
#pragma unroll
    for (int j = 0; j < 4; ++j) atomicAdd(&h[mono_key(scv[j]) >> 16], 1u);
  }
}

// Histogram of low 16 bits among keys whose top16 == prefix[b].
__global__ __launch_bounds__(256) void hist2_kernel(
    const float* __restrict__ score, unsigned int* __restrict__ ws) {
  int b = blockIdx.x / SLICES;
  int sl = blockIdx.x - b * SLICES;
  const float* s = score + b * HW;
  unsigned int pref = ws[OFF_PREFIX + b];
  unsigned int* h = ws + OFF_HIST2 + (b << 16);
  int base = sl * SLICE_LEN;
  for (int i = base + threadIdx.x; i < base + SLICE_LEN; i += 256) {
    unsigned int key = mono_key(s[i]);
    if ((key >> 16) == pref) atomicAdd(&h[key & 0xFFFFu], 1u);
  }
}

// Top-count select in a 65536-bin histogram via suffix scan of 1024 chunk sums.
// phase0: hist1, K=KSEL -> prefix, rem1.  phase1: hist2, K=rem1 -> Tkey, rem2.
__global__ __launch_bounds__(1024) void select_kernel(unsigned int* __restrict__ ws,
                                                      int phase) {
  int b = blockIdx.x;
  const unsigned int* h = ws + (phase ? OFF_HIST2 : OFF_HIST1) + (b << 16);
  unsigned int K = phase ? ws[OFF_REM1 + b] : (unsigned int)KSEL;

  __shared__ unsigned int suf[1024];
  __shared__ unsigned int s_chunk_idx, s_cum_above;
  __shared__ unsigned int bins[64];

  int t = threadIdx.x;
  unsigned int sum = 0;
#pragma unroll 8
  for (int i = 0; i < 64; ++i) sum += h[t * 64 + i];
  suf[t] = sum;
  __syncthreads();
  for (int off = 1; off < 1024; off <<= 1) {
    unsigned int v = (t + off < 1024) ? suf[t + off] : 0u;
    __syncthreads();
    suf[t] += v;
    __syncthreads();
  }
  unsigned int above = (t == 1023) ? 0u : suf[t + 1];
  if (suf[t] >= K && above < K) { s_chunk_idx = (unsigned int)t; s_cum_above = above; }
  __syncthreads();
  if (t < 64) bins[t] = h[s_chunk_idx * 64 + t];
  __syncthreads();
  if (t == 0) {
    unsigned int cum = s_cum_above;
    int d = 63;
    for (; d >= 0; --d) {
      if (cum + bins[d] >= K) break;
      cum += bins[d];
    }
    unsigned int binidx = s_chunk_idx * 64 + (unsigned int)d;
    if (phase == 0) {
      ws[OFF_PREFIX + b] = binidx;
      ws[OFF_REM1 + b] = K - cum;
    } else {
      ws[OFF_TKEY + b] = (ws[OFF_PREFIX + b] << 16) | binidx;
      ws[OFF_REM2 + b] = K - cum;
      ws[OFF_TIE + b] = 0u;
    }
  }
}

// Sum contribs of top-k (key > T, plus counted ties at key == T), then the
// last block to finish computes the final scalar (ticket + device atomics).
__global__ __launch_bounds__(256) void sum_finalize_kernel(
    const float* __restrict__ score, const float* __restrict__ contrib,
    unsigned int* __restrict__ ws,
    const float* __restrict__ dx, const float* __restrict__ dy,
    const float* __restrict__ dth, float* __restrict__ out) {
  int b = blockIdx.x / SLICES;
  int sl = blockIdx.x - b * SLICES;
  const float* s = score + b * HW;
  const float* ct = contrib + b * HW;
  unsigned int T = ws[OFF_TKEY + b];
  unsigned int rem2 = ws[OFF_REM2 + b];

  float partial = 0.f;
  int base = sl * SLICE_LEN;
  for (int i = base + threadIdx.x; i < base + SLICE_LEN; i += 256) {
    unsigned int key = mono_key(s[i]);
    if (key > T) {
      partial += ct[i];
    } else if (key == T) {
      unsigned int old = atomicAdd(&ws[OFF_TIE + b], 1u);
      if (old < rem2) partial += ct[i];
    }
  }

  __shared__ float red[256];
  red[threadIdx.x] = partial;
  __syncthreads();
  for (int off = 128; off > 0; off >>= 1) {
    if (threadIdx.x < (unsigned)off) red[threadIdx.x] += red[threadIdx.x + off];
    __syncthreads();
  }
  if (threadIdx.x == 0) {
    atomicAdd((float*)(ws + OFF_BSUMS) + b, red[0]);
    __threadfence();
    unsigned int t = atomicAdd(&ws[OFF_DONE], 1u);
    if (t == BATCH * SLICES - 1) {
      float ssum = 0.f;
      for (int i = 0; i < BATCH; ++i)
        ssum += atomicAdd((float*)(ws + OFF_BSUMS) + i, 0.0f);  // coherent read
      float align = ssum / (float)(BATCH * KSEL);
      float r1 = 0.f, r2 = 0.f;
      for (int i = 0; i < BATCH; ++i) {
        r1 += dx[i] * dx[i] + dy[i] * dy[i];
        r2 += dth[i] * dth[i];
      }
      out[0] = align + 0.1f * (r1 / (float)BATCH + r2 / (float)BATCH);
    }
  }
}

extern "C" void kernel_launch(void* const* d_in, const int* in_sizes, int n_in,
                              void* d_out, int out_size, void* d_ws, size_t ws_size,
                              hipStream_t stream) {
  const float* bev   = (const float*)d_in[0];
  const float* prior = (const float*)d_in[1];
  const float* dx    = (const float*)d_in[2];
  const float* dy    = (const float*)d_in[3];
  const float* dth   = (const float*)d_in[4];
  float* out = (float*)d_out;

  unsigned int* ws = (unsigned int*)d_ws;
  float* score   = (float*)ws + OFF_SCORE;
  float* contrib = (float*)ws + OFF_CONTRIB;

  zero_kernel<<<256, 256, 0, stream>>>(ws);
  stats_kernel<<<BATCH * BPB, 256, 0, stream>>>(bev, prior, score, contrib, ws);
  select_kernel<<<BATCH, 1024, 0, stream>>>(ws, 0);
  hist2_kernel<<<BATCH * SLICES, 256, 0, stream>>>(score, ws);
  select_kernel<<<BATCH, 1024, 0, stream>>>(ws, 1);
  sum_finalize_kernel<<<BATCH * SLICES, 256, 0, stream>>>(score, contrib, ws, dx, dy, dth, out);
}